// Round 4
// baseline (166.032 us; speedup 1.0000x reference)
//
#include <hip/hip_runtime.h>

// ---------------------------------------------------------------------------
// GMMConv forward — int8-gather, barrier-free-GEMM edition:
//  0) convert_W: Wp[j'][k-granule swizzled] into a 128 KB overlay at d_out.
//     B 16B-granules pre-swizzled (quad ^= row&3) so the LDS ds_read_b128 is
//     4-way instead of 8-way bank-conflicted (DMA must stay linear: rule =
//     swizzle global source + read side, never the global_load_lds dest).
//  1) gemm_fused v2: R3 accounting put gemm at ~39 us vs ~640 cy/wave of
//     MFMA — all stall: 2 syncthreads (vmcnt(0) drains) per ki with the
//     next B-DMA issued after the 2nd barrier (exposed L2 latency x8).
//     Now: Bs double-buffered (2x16KB), As XOR-swizzled 32KB (64KB total),
//     and NO barriers in the K-loop: each wave's DMA region == its read
//     region, so a per-wave counted s_waitcnt vmcnt(4) (never 0; next
//     tile's 4 DMAs stay in flight) is sufficient. Epilogue unchanged
//     (one syncthreads after the loop before qt reuses Bs).
//  2) edge_aggregate v4: v2/v3 showed time invariant (~41.5 us) across two
//     different chain-overlap schedules with VALU-issue-time conserved
//     (~22 us) -> probe the VALU component: gaussian was computed 4x
//     redundantly (lanes eg=0..3 duplicate edge fo). Now each lane computes
//     ONE kernel (kk=lane>>4) of edge fo, packs via 2 shfl_xor+or. If time
//     doesn't move, edge is LLC-random-BW-pinned (93MB @ ~2.4 TB/s).
//  Precision: math unchanged (same MFMA, same i8 quant) -> absmax 0.625.
// ---------------------------------------------------------------------------

typedef _Float16 f16;
typedef __attribute__((ext_vector_type(4))) _Float16 f16x4;
typedef __attribute__((ext_vector_type(8))) _Float16 f16x8;
typedef __attribute__((ext_vector_type(4))) float f32x4;

__device__ inline f16x4 cvt4h(float4 v) {
    f16x4 h;
    h.x = (f16)v.x; h.y = (f16)v.y; h.z = (f16)v.z; h.w = (f16)v.w;
    return h;
}

__device__ inline int dot4_i8(int a, int b) {
#if __has_builtin(__builtin_amdgcn_sdot4)
    return __builtin_amdgcn_sdot4(a, b, 0, false);
#else
    return (int)(char)(a)       * (int)(char)(b)
         + (int)(char)(a >> 8)  * (int)(char)(b >> 8)
         + (int)(char)(a >> 16) * (int)(char)(b >> 16)
         + (int)(char)(a >> 24) * (int)(char)(b >> 24);
#endif
}

// W_fc fp32 [256][256] -> Wp f16 [256][256], rows permuted, 16B k-granules
// swizzled within each 64B ki-slice: granule quad' = quad ^ (row&3).
// (k4 is an 8B f16x4 index; quad = bits 1..2 of k4 -> XOR (row&3)<<1.)
__global__ __launch_bounds__(256) void convert_W(
    const float* __restrict__ W, f16* __restrict__ Wp)
{
    const int gid = blockIdx.x * 256 + threadIdx.x;   // 64 blocks -> 16384
    const int jp = gid >> 6, k4 = gid & 63;
    const int wrow = ((jp & 3) << 6) | (jp >> 2);
    const int k4s = k4 ^ ((jp & 3) << 1);             // B bank swizzle
    reinterpret_cast<f16x4*>(Wp)[jp * 64 + k4s] =
        cvt4h(reinterpret_cast<const float4*>(W)[wrow * 64 + k4]);
}

// nfq[m][jp] = i8 quant of sum_k f16(feat[m][k]) * Wp[jp][k]
// sc[m][g]   = groupAbsmax / 127^2 for col group g = jp>>6
__global__ __launch_bounds__(256) void gemm_fused(
    const float* __restrict__ feat,   // fp32 [M][256]
    const f16* __restrict__ Wp,       // f16 [256][256] permuted+swizzled
    char* __restrict__ nfq,           // i8 [M][256]
    float* __restrict__ sc,           // f32 [M][4]
    int M)
{
    // As 32KB (row*512 + (kbyte ^ ((row&7)<<4))) + Bs double buffer 2x16KB
    __shared__ char smem[32768 + 2 * 16384];          // exactly 64 KB
    char* Asb = smem;
    char* BsB = smem + 32768;
    char* qt  = BsB;                  // epilogue reuses Bs (after sync)
    const int t    = threadIdx.x;
    const int lane = t & 63;
    const int wave = t >> 6;
    const int bm   = blockIdx.x * 64;
    const int l16  = lane & 15;
    const int quad = lane >> 4;
    const int wn   = wave * 64;

    size_t bsrc[4];
#pragma unroll
    for (int j = 0; j < 4; ++j)
        bsrc[j] = (size_t)(wave * 64 + j * 16 + (lane >> 2)) * 256 + (lane & 3) * 8;

    typedef __attribute__((address_space(3))) void lds_t;
    typedef const __attribute__((address_space(1))) void gm_t;

    // kick off B DMA for ki=0 into buf0, then stage A (fp32->f16, swizzled)
    // while it flies; the A-loads' own vmcnt drain retires these DMAs before
    // the prologue barrier.
#pragma unroll
    for (int j = 0; j < 4; ++j)
        __builtin_amdgcn_global_load_lds((gm_t*)(Wp + bsrc[j]),
            (lds_t*)(BsB + (wave * 4 + j) * 1024), 16, 0, 0);

#pragma unroll
    for (int it = 0; it < 8; ++it) {
        const int flat = it * 2048 + t * 8;
        const int row  = flat >> 8;              // 0..63
        const int koff = flat & 255;             // multiple of 8
        const float* src = feat + (size_t)min(bm + row, M - 1) * 256 + koff;
        const float4 a0 = *reinterpret_cast<const float4*>(src);
        const float4 a1 = *reinterpret_cast<const float4*>(src + 4);
        char* dst = Asb + row * 512 + ((koff * 2) ^ ((row & 7) << 4));
        *reinterpret_cast<f16x4*>(dst)     = cvt4h(a0);
        *reinterpret_cast<f16x4*>(dst + 8) = cvt4h(a1);
    }

    f32x4 acc[4][4];
#pragma unroll
    for (int mi = 0; mi < 4; ++mi)
#pragma unroll
        for (int ni = 0; ni < 4; ++ni)
            acc[mi][ni] = (f32x4){0.f, 0.f, 0.f, 0.f};

    __syncthreads();                  // As ready (Bs(0) already retired)

    const int axor = (l16 & 7) << 4;
    const int bxor = (l16 & 3) << 4;

    // K-loop: NO barriers. Wave-private Bs regions + counted vmcnt.
#pragma unroll
    for (int ki = 0; ki < 8; ++ki) {
        const char* bsb = BsB + ((ki & 1) << 14);
        if (ki < 7) {
            const int k0 = (ki + 1) * 32;
            char* dstb = BsB + (((ki + 1) & 1) << 14);
#pragma unroll
            for (int j = 0; j < 4; ++j)
                __builtin_amdgcn_global_load_lds((gm_t*)(Wp + bsrc[j] + k0),
                    (lds_t*)(dstb + (wave * 4 + j) * 1024), 16, 0, 0);
            __builtin_amdgcn_sched_barrier(0);
            asm volatile("s_waitcnt vmcnt(4)" ::: "memory");  // ki done, ki+1 flies
            __builtin_amdgcn_sched_barrier(0);
        } else {
            __builtin_amdgcn_sched_barrier(0);
            asm volatile("s_waitcnt vmcnt(0)" ::: "memory");  // last tile done
            __builtin_amdgcn_sched_barrier(0);
        }

        f16x8 af[4], bfr[4];
#pragma unroll
        for (int mi = 0; mi < 4; ++mi)
            af[mi] = *reinterpret_cast<const f16x8*>(
                Asb + (mi * 16 + l16) * 512 + ((ki * 64 + quad * 16) ^ axor));
#pragma unroll
        for (int ni = 0; ni < 4; ++ni)
            bfr[ni] = *reinterpret_cast<const f16x8*>(
                bsb + (wn + ni * 16 + l16) * 64 + ((quad << 4) ^ bxor));

#pragma unroll
        for (int mi = 0; mi < 4; ++mi)
#pragma unroll
            for (int ni = 0; ni < 4; ++ni)
                acc[mi][ni] = __builtin_amdgcn_mfma_f32_16x16x32_f16(
                    af[mi], bfr[ni], acc[mi][ni], 0, 0, 0);
    }

    __syncthreads();                  // all waves done with Bs -> qt may write

    // quantize: per (row, this wave's 64 cols) absmax
    // C/D layout: col = lane&15, row = quad*4 + reg  [m89; dtype-independent]
#pragma unroll
    for (int mi = 0; mi < 4; ++mi) {
#pragma unroll
        for (int r = 0; r < 4; ++r) {
            float am = 0.f;
#pragma unroll
            for (int ni = 0; ni < 4; ++ni)
                am = fmaxf(am, fabsf(acc[mi][ni][r]));
            am = fmaxf(am, __shfl_xor(am, 1));   // reduce over l16 (same quad)
            am = fmaxf(am, __shfl_xor(am, 2));
            am = fmaxf(am, __shfl_xor(am, 4));
            am = fmaxf(am, __shfl_xor(am, 8));
            const float sinv = am > 0.f ? 127.f / am : 0.f;
            const int rl = mi * 16 + quad * 4 + r;
#pragma unroll
            for (int ni = 0; ni < 4; ++ni)
                qt[rl * 256 + wn + ni * 16 + l16] =
                    (char)(int)__builtin_rintf(acc[mi][ni][r] * sinv);
            if (l16 == 0) {
                const int row = bm + rl;
                if (row < M) sc[row * 4 + wave] = am * (1.f / 16129.f);
            }
        }
    }
    __syncthreads();

    // coalesced i8 store: thread t -> row t>>2, 64 B chunk (t&3)
    {
        const int rl  = t >> 2;
        const int co  = (t & 3) * 64;
        const int row = bm + rl;
        if (row < M) {
            const int4* s4 = reinterpret_cast<const int4*>(qt + rl * 256 + co);
            int4* d4 = reinterpret_cast<int4*>(nfq + (size_t)row * 256 + co);
#pragma unroll
            for (int j = 0; j < 4; ++j) d4[j] = s4[j];
        }
    }
}

// Two dst nodes per wave, cross-node pipelined. lane = (eg = l>>4 : edge slot
// in group-of-4, fo = l&15 : feature quad). v4: gaussian deduplicated — each
// lane computes ONE kernel (kk = l>>4) of edge fo and the 4 bytes are packed
// across the kk-lanes with 2 shfl_xor|or (was: 4 redundant exp per lane).
__global__ __launch_bounds__(256) void edge_aggregate(
    const int* __restrict__ rowptr,
    const int* __restrict__ colind,
    const float* __restrict__ pseudo,   // [E][2]
    const char* __restrict__ nfq,       // i8 [N][256] permuted [f*4+k]
    const float* __restrict__ sc,       // f32 [N][4] group scales
    const float* __restrict__ mu,
    const float* __restrict__ inv_sigma,
    const float* __restrict__ bias,
    float* __restrict__ out,            // [N][64]
    int N)
{
    const int lane = threadIdx.x & 63;
    const int wid  = blockIdx.x * 4 + (threadIdx.x >> 6);
    const int na   = wid * 2;
    if (na >= N) return;                // wave-uniform; no barriers below
    const int nb   = na + 1;
    const bool hb  = nb < N;

    const int fo   = lane & 15;         // feature quad: f = 4*fo + r
    const int eg   = lane >> 4;         // edge slot within a group of 4
    const int qoff = fo << 4;           // byte offset into a 256 B nfq row
    const int goff = fo >> 2;           // scale group = f>>4

    // per-lane kernel constants: this lane owns kernel kk = lane>>4
    const int kk = lane >> 4;
    const float mx = mu[2 * kk], my = mu[2 * kk + 1];
    const float sa = inv_sigma[2 * kk], sb = inv_sigma[2 * kk + 1];
    const float C  = -0.5f * 1.4426950408889634f;     // fold log2(e)
    const float cx = C * sa * sa, cy = C * sb * sb;
    const int   sh = kk * 8;

    // packed 4-kernel gaussians for the 16-edge chunk at ec: lane computes
    // kernel kk of edge fo, then OR-combines bytes across the 4 kk-lanes.
    // Every lane ends holding the full i8x4 pack for edge fo.
    auto gpack = [&](int ec, int e0, int e1) -> int {
        const int exm = ec + fo;
        const bool gv = exm < e1;
        const int safe = (e1 > e0) ? (e1 - 1) : 0;
        const int ex  = gv ? exm : safe;
        const float2 p = *reinterpret_cast<const float2*>(pseudo + 2 * (size_t)ex);
        const float dx = p.x - mx, dy = p.y - my;
        const float g = exp2f(fmaf(dy * dy, cy, dx * dx * cx));
        int b = gv ? (((int)(g * 127.f + 0.5f)) << sh) : 0;
        b |= __shfl_xor(b, 16);
        b |= __shfl_xor(b, 32);
        return b;
    };

    const int ea0 = rowptr[na];
    const int ea1 = rowptr[na + 1];
    const int eb0 = ea1;
    const int eb1 = hb ? rowptr[nb + 1] : ea1;

    // ---- stage BOTH nodes' first chunks up front (independent loads)
    const int safea = (ea1 > ea0) ? (ea1 - 1) : 0;
    int cfo_a = colind[min(ea0 + fo, safea)];
    int cfo_b = 0, gpk_b = 0;
    if (hb) {
        const int safeb = (eb1 > eb0) ? (eb1 - 1) : 0;
        cfo_b = colind[min(eb0 + fo, safeb)];
        gpk_b = gpack(eb0, eb0, eb1);
    }
    int gpk_a = gpack(ea0, ea0, ea1);

    // ---- node a
    float a0 = 0.f, a1 = 0.f, a2 = 0.f, a3 = 0.f;
    {
        int gpk = gpk_a, cfo = cfo_a;
        for (int ec = ea0; ec < ea1; ec += 16) {
            // issue this chunk's gathers first (c arrived last iteration)
            int4  q[4];
            float s[4];
            int   gq[4];
#pragma unroll
            for (int gi = 0; gi < 4; ++gi) {
                const int c = __shfl(cfo, gi * 4 + eg);
                q[gi]  = *reinterpret_cast<const int4*>(
                             nfq + ((size_t)c << 8) + qoff);
                s[gi]  = sc[c * 4 + goff];
                gq[gi] = __shfl(gpk, gi * 4 + eg);
            }
            // prefetch next chunk (loads fly under the dots below)
            const int ecn = ec + 16;
            int gpk_n = 0, cfo_n = cfo;
            if (ecn < ea1) {
                cfo_n = colind[min(ecn + fo, ea1 - 1)];
                gpk_n = gpack(ecn, ea0, ea1);
            }
#pragma unroll
            for (int gi = 0; gi < 4; ++gi) {
                a0 = fmaf(s[gi], (float)dot4_i8(q[gi].x, gq[gi]), a0);
                a1 = fmaf(s[gi], (float)dot4_i8(q[gi].y, gq[gi]), a1);
                a2 = fmaf(s[gi], (float)dot4_i8(q[gi].z, gq[gi]), a2);
                a3 = fmaf(s[gi], (float)dot4_i8(q[gi].w, gq[gi]), a3);
            }
            gpk = gpk_n; cfo = cfo_n;
        }
    }
    // reduce over the 4 edge slots and store node a
    a0 += __shfl_xor(a0, 16); a0 += __shfl_xor(a0, 32);
    a1 += __shfl_xor(a1, 16); a1 += __shfl_xor(a1, 32);
    a2 += __shfl_xor(a2, 16); a2 += __shfl_xor(a2, 32);
    a3 += __shfl_xor(a3, 16); a3 += __shfl_xor(a3, 32);
    if (lane < 16) {
        const float4 b4 = reinterpret_cast<const float4*>(bias)[fo];
        float4 o;
        o.x = a0 + b4.x; o.y = a1 + b4.y; o.z = a2 + b4.z; o.w = a3 + b4.w;
        reinterpret_cast<float4*>(out + ((size_t)na << 6))[fo] = o;
    }

    // ---- node b (first chunk's colind/pseudo already resident)
    if (!hb) return;
    float b0 = 0.f, b1 = 0.f, b2 = 0.f, b3 = 0.f;
    {
        int gpk = gpk_b, cfo = cfo_b;
        for (int ec = eb0; ec < eb1; ec += 16) {
            int4  q[4];
            float s[4];
            int   gq[4];
#pragma unroll
            for (int gi = 0; gi < 4; ++gi) {
                const int c = __shfl(cfo, gi * 4 + eg);
                q[gi]  = *reinterpret_cast<const int4*>(
                             nfq + ((size_t)c << 8) + qoff);
                s[gi]  = sc[c * 4 + goff];
                gq[gi] = __shfl(gpk, gi * 4 + eg);
            }
            const int ecn = ec + 16;
            int gpk_n = 0, cfo_n = cfo;
            if (ecn < eb1) {
                cfo_n = colind[min(ecn + fo, eb1 - 1)];
                gpk_n = gpack(ecn, eb0, eb1);
            }
#pragma unroll
            for (int gi = 0; gi < 4; ++gi) {
                b0 = fmaf(s[gi], (float)dot4_i8(q[gi].x, gq[gi]), b0);
                b1 = fmaf(s[gi], (float)dot4_i8(q[gi].y, gq[gi]), b1);
                b2 = fmaf(s[gi], (float)dot4_i8(q[gi].z, gq[gi]), b2);
                b3 = fmaf(s[gi], (float)dot4_i8(q[gi].w, gq[gi]), b3);
            }
            gpk = gpk_n; cfo = cfo_n;
        }
    }
    b0 += __shfl_xor(b0, 16); b0 += __shfl_xor(b0, 32);
    b1 += __shfl_xor(b1, 16); b1 += __shfl_xor(b1, 32);
    b2 += __shfl_xor(b2, 16); b2 += __shfl_xor(b2, 32);
    b3 += __shfl_xor(b3, 16); b3 += __shfl_xor(b3, 32);
    if (lane < 16) {
        const float4 b4 = reinterpret_cast<const float4*>(bias)[fo];
        float4 o;
        o.x = b0 + b4.x; o.y = b1 + b4.y; o.z = b2 + b4.z; o.w = b3 + b4.w;
        reinterpret_cast<float4*>(out + ((size_t)nb << 6))[fo] = o;
    }
}

extern "C" void kernel_launch(void* const* d_in, const int* in_sizes, int n_in,
                              void* d_out, int out_size, void* d_ws, size_t ws_size,
                              hipStream_t stream)
{
    const int*   rowptr    = (const int*)d_in[0];
    const int*   colind    = (const int*)d_in[1];
    // d_in[2] colptr, d_in[3] rowind, d_in[4] permute: inert in forward math
    const float* feat      = (const float*)d_in[5];
    const float* pseudo    = (const float*)d_in[6];
    const float* W_fc      = (const float*)d_in[7];
    const float* mu        = (const float*)d_in[8];
    const float* inv_sigma = (const float*)d_in[9];
    const float* bias      = (const float*)d_in[10];
    float* out = (float*)d_out;

    const int N = in_sizes[0] - 1;        // 50000
    char*  nfq = (char*)d_ws;             // i8 [N][256] = 12.8 MB
    float* sc  = (float*)(nfq + (size_t)N * 256);  // f32 [N][4] = 0.8 MB
    f16*   Wp  = (f16*)d_out;             // 128 KB overlay; edge rewrites
                                          // all of d_out afterwards

    hipLaunchKernelGGL(convert_W, dim3(64), dim3(256), 0, stream, W_fc, Wp);

    hipLaunchKernelGGL(gemm_fused, dim3((N + 63) / 64), dim3(256), 0, stream,
                       feat, Wp, nfq, sc, N);

    // 4 waves/block, 2 nodes/wave -> 8 nodes/block
    hipLaunchKernelGGL(edge_aggregate, dim3((N + 7) / 8), dim3(256), 0, stream,
                       rowptr, colind, pseudo, nfq, sc, mu, inv_sigma, bias, out, N);
}

// Round 5
// 163.136 us; speedup vs baseline: 1.0178x; 1.0178x over previous
//
#include <hip/hip_runtime.h>

// ---------------------------------------------------------------------------
// GMMConv forward — int8-gather, register-epilogue edition:
//  0) convert_W: Wp row permutation REMAPPED so the gemm wave's (l16, ni)
//     fragment = (feature f = wave*16+l16, kernel k = ni). Each lane's 4
//     ni-values are then the 4 bytes of ONE nfq dword -> epilogue packs in
//     registers and stores straight to global (no LDS transpose at all).
//     wrow = ((jp>>4)&3)*64 + ((jp>>6)<<4) + (jp&15); granule XOR swizzle
//     (bank fix) unchanged, keyed on placed row jp.
//  1) gemm_fused v3: R4 proved the K-loop barriers were NOT the cost (flat
//     at ~40 us with and without them). New suspects attacked together:
//     epilogue DS work (64 ds_write_b8 + 64 dependent shfl + 2 barriers +
//     LDS round-trip) -> replaced by register pack + coalesced dword
//     stores; LDS 64->48 KB (single wave-private Bs buffer; read-before-
//     overwrite enforced by lgkmcnt(0)+sched_barrier before next DMA) ->
//     3 blocks/CU instead of 2 (+50% latency-hiding waves).
//     Scale grouping unchanged: wave's 64 cols = f in [16w,16w+16) x k
//     -> group g = f>>4 = wave (same set as before, bit-identical quant).
//  2) edge_aggregate v4 (unchanged): schedule-invariant ~41 us across three
//     schedules -> treated as LLC-equilibrium-pinned; not touched this round.
//  Precision: math bit-identical -> absmax 0.625.
// ---------------------------------------------------------------------------

typedef _Float16 f16;
typedef __attribute__((ext_vector_type(4))) _Float16 f16x4;
typedef __attribute__((ext_vector_type(8))) _Float16 f16x8;
typedef __attribute__((ext_vector_type(4))) float f32x4;

__device__ inline f16x4 cvt4h(float4 v) {
    f16x4 h;
    h.x = (f16)v.x; h.y = (f16)v.y; h.z = (f16)v.z; h.w = (f16)v.w;
    return h;
}

__device__ inline int dot4_i8(int a, int b) {
#if __has_builtin(__builtin_amdgcn_sdot4)
    return __builtin_amdgcn_sdot4(a, b, 0, false);
#else
    return (int)(char)(a)       * (int)(char)(b)
         + (int)(char)(a >> 8)  * (int)(char)(b >> 8)
         + (int)(char)(a >> 16) * (int)(char)(b >> 16)
         + (int)(char)(a >> 24) * (int)(char)(b >> 24);
#endif
}

// W_fc fp32 [256][256] -> Wp f16 [256][256].
// Placed row jp holds logical W-row (k*64 + f) with k=(jp>>4)&3,
// f=(jp>>6)*16 + (jp&15)  ->  gemm lane (wave,l16,ni) owns (f=wave*16+l16,
// k=ni), i.e. the 4 bytes of output dword f. 16B k-granules XOR-swizzled
// within each 64B ki-slice (granule ^= jp&3) for LDS bank spread.
__global__ __launch_bounds__(256) void convert_W(
    const float* __restrict__ W, f16* __restrict__ Wp)
{
    const int gid = blockIdx.x * 256 + threadIdx.x;   // 64 blocks -> 16384
    const int jp = gid >> 6, k4 = gid & 63;
    const int wrow = ((jp >> 4) & 3) * 64 + ((jp >> 6) << 4) + (jp & 15);
    const int k4s = k4 ^ ((jp & 3) << 1);             // B bank swizzle
    reinterpret_cast<f16x4*>(Wp)[jp * 64 + k4s] =
        cvt4h(reinterpret_cast<const float4*>(W)[wrow * 64 + k4]);
}

// nfq[m] dword f: byte k = i8 quant of node_feat[m][k][f]
// sc[m][g] = groupAbsmax / 127^2 for feature group g = f>>4
__global__ __launch_bounds__(256) void gemm_fused(
    const float* __restrict__ feat,   // fp32 [M][256]
    const f16* __restrict__ Wp,       // f16 [256][256] permuted+swizzled
    char* __restrict__ nfq,           // i8 [M][256]
    float* __restrict__ sc,           // f32 [M][4]
    int M)
{
    // As 32KB swizzled + single Bs 16KB (wave-private quarters) = 48 KB
    __shared__ char smem[32768 + 16384];
    char* Asb = smem;
    char* Bsb = smem + 32768;
    const int t    = threadIdx.x;
    const int lane = t & 63;
    const int wave = t >> 6;
    const int bm   = blockIdx.x * 64;
    const int l16  = lane & 15;
    const int quad = lane >> 4;
    const int wn   = wave * 64;

    size_t bsrc[4];
#pragma unroll
    for (int j = 0; j < 4; ++j)
        bsrc[j] = (size_t)(wave * 64 + j * 16 + (lane >> 2)) * 256 + (lane & 3) * 8;

    typedef __attribute__((address_space(3))) void lds_t;
    typedef const __attribute__((address_space(1))) void gm_t;

    // kick off B DMA for ki=0, then stage A (fp32->f16, swizzled) while it
    // flies; the A-loads' in-order vmcnt retirement also retires these DMAs
    // before the prologue barrier.
#pragma unroll
    for (int j = 0; j < 4; ++j)
        __builtin_amdgcn_global_load_lds((gm_t*)(Wp + bsrc[j]),
            (lds_t*)(Bsb + (wave * 4 + j) * 1024), 16, 0, 0);

#pragma unroll
    for (int it = 0; it < 8; ++it) {
        const int flat = it * 2048 + t * 8;
        const int row  = flat >> 8;              // 0..63
        const int koff = flat & 255;             // multiple of 8
        const float* src = feat + (size_t)min(bm + row, M - 1) * 256 + koff;
        const float4 a0 = *reinterpret_cast<const float4*>(src);
        const float4 a1 = *reinterpret_cast<const float4*>(src + 4);
        char* dst = Asb + row * 512 + ((koff * 2) ^ ((row & 7) << 4));
        *reinterpret_cast<f16x4*>(dst)     = cvt4h(a0);
        *reinterpret_cast<f16x4*>(dst + 8) = cvt4h(a1);
    }

    f32x4 acc[4][4];
#pragma unroll
    for (int mi = 0; mi < 4; ++mi)
#pragma unroll
        for (int ni = 0; ni < 4; ++ni)
            acc[mi][ni] = (f32x4){0.f, 0.f, 0.f, 0.f};

    __syncthreads();                  // As ready (Bs(0) already retired)

    const int axor = (l16 & 7) << 4;
    const int bxor = (l16 & 3) << 4;

    // K-loop: no block barriers. Single wave-private Bs region; the next
    // tile's DMA is issued only after this tile's ds_reads have completed
    // (lgkmcnt(0) + sched_barrier), so write-before-read cannot occur.
#pragma unroll
    for (int ki = 0; ki < 8; ++ki) {
        __builtin_amdgcn_sched_barrier(0);
        asm volatile("s_waitcnt vmcnt(0)" ::: "memory");   // Bs(ki) landed
        __builtin_amdgcn_sched_barrier(0);

        f16x8 af[4], bfr[4];
#pragma unroll
        for (int mi = 0; mi < 4; ++mi)
            af[mi] = *reinterpret_cast<const f16x8*>(
                Asb + (mi * 16 + l16) * 512 + ((ki * 64 + quad * 16) ^ axor));
#pragma unroll
        for (int ni = 0; ni < 4; ++ni)
            bfr[ni] = *reinterpret_cast<const f16x8*>(
                Bsb + (wn + ni * 16 + l16) * 64 + ((quad << 4) ^ bxor));

        __builtin_amdgcn_sched_barrier(0);
        asm volatile("s_waitcnt lgkmcnt(0)" ::: "memory"); // reads done -> Bs free
        __builtin_amdgcn_sched_barrier(0);

        if (ki < 7) {
            const int k0 = (ki + 1) * 32;
#pragma unroll
            for (int j = 0; j < 4; ++j)
                __builtin_amdgcn_global_load_lds((gm_t*)(Wp + bsrc[j] + k0),
                    (lds_t*)(Bsb + (wave * 4 + j) * 1024), 16, 0, 0);
        }

#pragma unroll
        for (int mi = 0; mi < 4; ++mi)
#pragma unroll
            for (int ni = 0; ni < 4; ++ni)
                acc[mi][ni] = __builtin_amdgcn_mfma_f32_16x16x32_f16(
                    af[mi], bfr[ni], acc[mi][ni], 0, 0, 0);
    }

    // Register epilogue: no LDS, no barriers.
    // C/D layout: col = lane&15, row = quad*4 + reg  [m89; dtype-independent]
    // This lane's 4 ni-values = bytes k=0..3 of output dword f = wave*16+l16.
#pragma unroll
    for (int mi = 0; mi < 4; ++mi) {
#pragma unroll
        for (int r = 0; r < 4; ++r) {
            float am = 0.f;
#pragma unroll
            for (int ni = 0; ni < 4; ++ni)
                am = fmaxf(am, fabsf(acc[mi][ni][r]));
            am = fmaxf(am, __shfl_xor(am, 1));   // reduce over l16 (same quad)
            am = fmaxf(am, __shfl_xor(am, 2));
            am = fmaxf(am, __shfl_xor(am, 4));
            am = fmaxf(am, __shfl_xor(am, 8));
            const float sinv = am > 0.f ? 127.f / am : 0.f;
            unsigned pk = 0;
#pragma unroll
            for (int k = 0; k < 4; ++k) {
                const int b = (int)__builtin_rintf(acc[mi][k][r] * sinv);
                pk |= (unsigned)(b & 255) << (8 * k);
            }
            const int rl  = mi * 16 + quad * 4 + r;
            const int row = bm + rl;
            if (row < M) {
                reinterpret_cast<unsigned*>(nfq + (size_t)row * 256)
                    [wave * 16 + l16] = pk;
                if (l16 == 0) sc[row * 4 + wave] = am * (1.f / 16129.f);
            }
        }
    }
}

// Two dst nodes per wave, cross-node pipelined. lane = (eg = l>>4 : edge slot
// in group-of-4, fo = l&15 : feature quad). v4: gaussian deduplicated — each
// lane computes ONE kernel (kk = l>>4) of edge fo and the 4 bytes are packed
// across the kk-lanes with 2 shfl_xor|or.
__global__ __launch_bounds__(256) void edge_aggregate(
    const int* __restrict__ rowptr,
    const int* __restrict__ colind,
    const float* __restrict__ pseudo,   // [E][2]
    const char* __restrict__ nfq,       // i8 [N][256] dword f, byte k
    const float* __restrict__ sc,       // f32 [N][4] group scales
    const float* __restrict__ mu,
    const float* __restrict__ inv_sigma,
    const float* __restrict__ bias,
    float* __restrict__ out,            // [N][64]
    int N)
{
    const int lane = threadIdx.x & 63;
    const int wid  = blockIdx.x * 4 + (threadIdx.x >> 6);
    const int na   = wid * 2;
    if (na >= N) return;                // wave-uniform; no barriers below
    const int nb   = na + 1;
    const bool hb  = nb < N;

    const int fo   = lane & 15;         // feature quad: f = 4*fo + r
    const int eg   = lane >> 4;         // edge slot within a group of 4
    const int qoff = fo << 4;           // byte offset into a 256 B nfq row
    const int goff = fo >> 2;           // scale group = f>>4

    // per-lane kernel constants: this lane owns kernel kk = lane>>4
    const int kk = lane >> 4;
    const float mx = mu[2 * kk], my = mu[2 * kk + 1];
    const float sa = inv_sigma[2 * kk], sb = inv_sigma[2 * kk + 1];
    const float C  = -0.5f * 1.4426950408889634f;     // fold log2(e)
    const float cx = C * sa * sa, cy = C * sb * sb;
    const int   sh = kk * 8;

    // packed 4-kernel gaussians for the 16-edge chunk at ec: lane computes
    // kernel kk of edge fo, then OR-combines bytes across the 4 kk-lanes.
    auto gpack = [&](int ec, int e0, int e1) -> int {
        const int exm = ec + fo;
        const bool gv = exm < e1;
        const int safe = (e1 > e0) ? (e1 - 1) : 0;
        const int ex  = gv ? exm : safe;
        const float2 p = *reinterpret_cast<const float2*>(pseudo + 2 * (size_t)ex);
        const float dx = p.x - mx, dy = p.y - my;
        const float g = exp2f(fmaf(dy * dy, cy, dx * dx * cx));
        int b = gv ? (((int)(g * 127.f + 0.5f)) << sh) : 0;
        b |= __shfl_xor(b, 16);
        b |= __shfl_xor(b, 32);
        return b;
    };

    const int ea0 = rowptr[na];
    const int ea1 = rowptr[na + 1];
    const int eb0 = ea1;
    const int eb1 = hb ? rowptr[nb + 1] : ea1;

    // ---- stage BOTH nodes' first chunks up front (independent loads)
    const int safea = (ea1 > ea0) ? (ea1 - 1) : 0;
    int cfo_a = colind[min(ea0 + fo, safea)];
    int cfo_b = 0, gpk_b = 0;
    if (hb) {
        const int safeb = (eb1 > eb0) ? (eb1 - 1) : 0;
        cfo_b = colind[min(eb0 + fo, safeb)];
        gpk_b = gpack(eb0, eb0, eb1);
    }
    int gpk_a = gpack(ea0, ea0, ea1);

    // ---- node a
    float a0 = 0.f, a1 = 0.f, a2 = 0.f, a3 = 0.f;
    {
        int gpk = gpk_a, cfo = cfo_a;
        for (int ec = ea0; ec < ea1; ec += 16) {
            int4  q[4];
            float s[4];
            int   gq[4];
#pragma unroll
            for (int gi = 0; gi < 4; ++gi) {
                const int c = __shfl(cfo, gi * 4 + eg);
                q[gi]  = *reinterpret_cast<const int4*>(
                             nfq + ((size_t)c << 8) + qoff);
                s[gi]  = sc[c * 4 + goff];
                gq[gi] = __shfl(gpk, gi * 4 + eg);
            }
            const int ecn = ec + 16;
            int gpk_n = 0, cfo_n = cfo;
            if (ecn < ea1) {
                cfo_n = colind[min(ecn + fo, ea1 - 1)];
                gpk_n = gpack(ecn, ea0, ea1);
            }
#pragma unroll
            for (int gi = 0; gi < 4; ++gi) {
                a0 = fmaf(s[gi], (float)dot4_i8(q[gi].x, gq[gi]), a0);
                a1 = fmaf(s[gi], (float)dot4_i8(q[gi].y, gq[gi]), a1);
                a2 = fmaf(s[gi], (float)dot4_i8(q[gi].z, gq[gi]), a2);
                a3 = fmaf(s[gi], (float)dot4_i8(q[gi].w, gq[gi]), a3);
            }
            gpk = gpk_n; cfo = cfo_n;
        }
    }
    a0 += __shfl_xor(a0, 16); a0 += __shfl_xor(a0, 32);
    a1 += __shfl_xor(a1, 16); a1 += __shfl_xor(a1, 32);
    a2 += __shfl_xor(a2, 16); a2 += __shfl_xor(a2, 32);
    a3 += __shfl_xor(a3, 16); a3 += __shfl_xor(a3, 32);
    if (lane < 16) {
        const float4 b4 = reinterpret_cast<const float4*>(bias)[fo];
        float4 o;
        o.x = a0 + b4.x; o.y = a1 + b4.y; o.z = a2 + b4.z; o.w = a3 + b4.w;
        reinterpret_cast<float4*>(out + ((size_t)na << 6))[fo] = o;
    }

    // ---- node b (first chunk's colind/pseudo already resident)
    if (!hb) return;
    float b0 = 0.f, b1 = 0.f, b2 = 0.f, b3 = 0.f;
    {
        int gpk = gpk_b, cfo = cfo_b;
        for (int ec = eb0; ec < eb1; ec += 16) {
            int4  q[4];
            float s[4];
            int   gq[4];
#pragma unroll
            for (int gi = 0; gi < 4; ++gi) {
                const int c = __shfl(cfo, gi * 4 + eg);
                q[gi]  = *reinterpret_cast<const int4*>(
                             nfq + ((size_t)c << 8) + qoff);
                s[gi]  = sc[c * 4 + goff];
                gq[gi] = __shfl(gpk, gi * 4 + eg);
            }
            const int ecn = ec + 16;
            int gpk_n = 0, cfo_n = cfo;
            if (ecn < eb1) {
                cfo_n = colind[min(ecn + fo, eb1 - 1)];
                gpk_n = gpack(ecn, eb0, eb1);
            }
#pragma unroll
            for (int gi = 0; gi < 4; ++gi) {
                b0 = fmaf(s[gi], (float)dot4_i8(q[gi].x, gq[gi]), b0);
                b1 = fmaf(s[gi], (float)dot4_i8(q[gi].y, gq[gi]), b1);
                b2 = fmaf(s[gi], (float)dot4_i8(q[gi].z, gq[gi]), b2);
                b3 = fmaf(s[gi], (float)dot4_i8(q[gi].w, gq[gi]), b3);
            }
            gpk = gpk_n; cfo = cfo_n;
        }
    }
    b0 += __shfl_xor(b0, 16); b0 += __shfl_xor(b0, 32);
    b1 += __shfl_xor(b1, 16); b1 += __shfl_xor(b1, 32);
    b2 += __shfl_xor(b2, 16); b2 += __shfl_xor(b2, 32);
    b3 += __shfl_xor(b3, 16); b3 += __shfl_xor(b3, 32);
    if (lane < 16) {
        const float4 b4 = reinterpret_cast<const float4*>(bias)[fo];
        float4 o;
        o.x = b0 + b4.x; o.y = b1 + b4.y; o.z = b2 + b4.z; o.w = b3 + b4.w;
        reinterpret_cast<float4*>(out + ((size_t)nb << 6))[fo] = o;
    }
}

extern "C" void kernel_launch(void* const* d_in, const int* in_sizes, int n_in,
                              void* d_out, int out_size, void* d_ws, size_t ws_size,
                              hipStream_t stream)
{
    const int*   rowptr    = (const int*)d_in[0];
    const int*   colind    = (const int*)d_in[1];
    // d_in[2] colptr, d_in[3] rowind, d_in[4] permute: inert in forward math
    const float* feat      = (const float*)d_in[5];
    const float* pseudo    = (const float*)d_in[6];
    const float* W_fc      = (const float*)d_in[7];
    const float* mu        = (const float*)d_in[8];
    const float* inv_sigma = (const float*)d_in[9];
    const float* bias      = (const float*)d_in[10];
    float* out = (float*)d_out;

    const int N = in_sizes[0] - 1;        // 50000
    char*  nfq = (char*)d_ws;             // i8 [N][256] = 12.8 MB
    float* sc  = (float*)(nfq + (size_t)N * 256);  // f32 [N][4] = 0.8 MB
    f16*   Wp  = (f16*)d_out;             // 128 KB overlay; edge rewrites
                                          // all of d_out afterwards

    hipLaunchKernelGGL(convert_W, dim3(64), dim3(256), 0, stream, W_fc, Wp);

    hipLaunchKernelGGL(gemm_fused, dim3((N + 63) / 64), dim3(256), 0, stream,
                       feat, Wp, nfq, sc, N);

    // 4 waves/block, 2 nodes/wave -> 8 nodes/block
    hipLaunchKernelGGL(edge_aggregate, dim3((N + 7) / 8), dim3(256), 0, stream,
                       rowptr, colind, pseudo, nfq, sc, mu, inv_sigma, bias, out, N);
}